// Round 5
// baseline (3219.165 us; speedup 1.0000x reference)
//
#include <hip/hip_runtime.h>
#include <hip/hip_bf16.h>
#include <cstdint>
#include <cstddef>

// ---------------------------------------------------------------------------
// DisentangledMultiHeadAttention: B=8, H=2, T=2048, D=2048, C=4096
// 256x256-tile bf16 MFMA GEMM, 8 waves (2M x 4N), K-slab ring (4 x K=32,
// 128KB LDS), m201-style sub-phase schedule:
//   per slab: 2 sub-phases, each {ds_read frags for THIS sub-phase's MFMA
//   (8 or 4 x b128) ; 2 x global_load_lds stage of slab p+3 ; barrier ;
//   lgkmcnt(0)+sched_barrier ; setprio(1) 16 MFMA setprio(0) ; barrier}.
//   vmcnt(8) once per slab (counted, never 0 in main loop).
// LDS is FRAGMENT-MAJOR: each 1KB MFMA fragment contiguous; lane l reads
// base + l*16B (conflict-free); gld_lds writes the identical pattern via
// per-lane pre-swizzled global source (both-sides rule).
// v stored TRANSPOSED so PV is NT; softmax emits bf16 probs for PV.
// ---------------------------------------------------------------------------

typedef short short8_t __attribute__((ext_vector_type(8)));
typedef float f32x4   __attribute__((ext_vector_type(4)));

__device__ __forceinline__ short f2bf(float f) {
  unsigned u = __builtin_bit_cast(unsigned, f);
  u = (u + 0x7FFFu + ((u >> 16) & 1u)) >> 16;   // round-to-nearest-even
  return (short)u;
}

__device__ __forceinline__ short8_t cvt8(float4 a, float4 b) {
  short8_t r;
  r[0] = f2bf(a.x); r[1] = f2bf(a.y); r[2] = f2bf(a.z); r[3] = f2bf(a.w);
  r[4] = f2bf(b.x); r[5] = f2bf(b.y); r[6] = f2bf(b.z); r[7] = f2bf(b.w);
  return r;
}

__device__ __forceinline__ void gld_lds16(const void* g, void* l) {
  __builtin_amdgcn_global_load_lds(
      (const __attribute__((address_space(1))) void*)g,
      (__attribute__((address_space(3))) void*)l, 16, 0, 0);
}

// fp32 -> bf16 bulk convert, 8 elem/thread, grid-stride
__global__ __launch_bounds__(256)
void cvt_f32_bf16(const float* __restrict__ src, short* __restrict__ dst, int n8) {
  for (int i = blockIdx.x * blockDim.x + threadIdx.x; i < n8;
       i += gridDim.x * blockDim.x) {
    const float4* p = (const float4*)(src + (size_t)i * 8);
    float4 a = p[0], b = p[1];
    *(short8_t*)(dst + (size_t)i * 8) = cvt8(a, b);
  }
}

// MODE 0: q/k proj  C=bf16 (b,h,t,d)                 K=4096
// MODE 2: v proj    C=bf16 (b,h,d,s) [transposed]    K=4096
// MODE 3: scores    C=f32 scale+bias -> attn (d_out) K=2048, batched z
// MODE 4: PV        C=bf16 (b*T+t, h*D+d)            K=2048, batched z
// MODE 5: out proj  C=f32 y (d_out)                  K=4096
template<int MODE>
__global__ __launch_bounds__(512, 2)
void gemm256(const short* __restrict__ Ag, const short* __restrict__ Bg,
             void* __restrict__ Cg, const float* __restrict__ bias) {
  constexpr int K  = (MODE == 3 || MODE == 4) ? 2048 : 4096;
  constexpr int NS = K / 32;   // K-slabs

  // ring: 4 slots x 32KB; per slot: A frags [16x512 shorts], B frags after.
  __shared__ short lds[65536];

  const int tid = threadIdx.x;

  // T1: bijective XCD swizzle (gridDim.x = 1024, divisible by 8)
  const int bid = blockIdx.x;
  const int id  = (bid & 7) * (gridDim.x >> 3) + (bid >> 3);

  int m0, n0, z = 0;
  size_t aoff = 0, boff = 0;
  if constexpr (MODE == 3 || MODE == 4) {
    z  = id >> 6;                       // 16 batches
    m0 = ((id >> 3) & 7) << 8;          // 8 m-tiles
    n0 = (id & 7) << 8;                 // 8 n-tiles
    aoff = boff = (size_t)z << 22;
  } else {
    m0 = (id >> 4) << 8;                // 64 m-tiles
    n0 = (id & 15) << 8;                // 16 n-tiles (n fastest: A-panel reuse)
  }

  const int l = tid & 63;
  const int w = tid >> 6;               // wave id 0..7

  // ---- staging (frag-major): frag f of a slab = rows [f*16, f*16+16) x k32,
  //      stored lane-ordered: lane l holds (row f*16+(l&15), k (l>>4)*8..+7).
  //      Wave w stages A frags {2w, 2w+1} and B frags {2w, 2w+1} per slab.
  const int srow = l & 15;
  const int skol = (l >> 4) * 8;
  const short* ApS  = Ag + aoff + (size_t)(m0 + 2 * w * 16 + srow) * K + skol;
  const short* ApS2 = ApS + (size_t)16 * K;
  const short* BpS  = Bg + boff + (size_t)(n0 + 2 * w * 16 + srow) * K + skol;
  const short* BpS2 = BpS + (size_t)16 * K;

  auto STAGE0 = [&](int t) {           // first halves (A frag 2w, B frag 2w)
    const int s = (t & 3) << 14;
    const int k = t * 32;
    gld_lds16(ApS + k, &lds[s + 2 * w * 512]);
    gld_lds16(BpS + k, &lds[s + 8192 + 2 * w * 512]);
  };
  auto STAGE1 = [&](int t) {           // second halves (frags 2w+1)
    const int s = (t & 3) << 14;
    const int k = t * 32;
    gld_lds16(ApS2 + k, &lds[s + (2 * w + 1) * 512]);
    gld_lds16(BpS2 + k, &lds[s + 8192 + (2 * w + 1) * 512]);
  };

  // ---- fragment read bases (conflict-free: base + l*16B) ----
  const int wmF = (tid >> 8) * 8;         // wave m frag base (0 / 8)
  const int wnF = ((tid >> 6) & 3) * 4;   // wave n frag base (0/4/8/12)
  const int l8  = l * 8;

  f32x4 acc[8][4] = {};

  STAGE0(0); STAGE1(0); STAGE0(1); STAGE1(1); STAGE0(2); STAGE1(2);
  asm volatile("s_waitcnt vmcnt(8)" ::: "memory");   // slab 0 landed
  __builtin_amdgcn_s_barrier();

  for (int p = 0; p < NS; ++p) {
    const int slot = (p & 3) << 14;
    short8_t A4[4], B4[4], A8[4];

    // ---- sub-phase 0: read B (all n) + A lower half; stage; MFMA mh=0 ----
#pragma unroll
    for (int n = 0; n < 4; ++n)
      B4[n] = *(const short8_t*)&lds[slot + 8192 + (wnF + n) * 512 + l8];
#pragma unroll
    for (int i = 0; i < 4; ++i)
      A4[i] = *(const short8_t*)&lds[slot + (wmF + i) * 512 + l8];
    if (p + 3 < NS) STAGE0(p + 3);
    __builtin_amdgcn_sched_barrier(0);
    __builtin_amdgcn_s_barrier();
    asm volatile("s_waitcnt lgkmcnt(0)" ::: "memory");
    __builtin_amdgcn_sched_barrier(0);
    __builtin_amdgcn_s_setprio(1);
#pragma unroll
    for (int i = 0; i < 4; ++i)
#pragma unroll
      for (int n = 0; n < 4; ++n)
        acc[i][n] = __builtin_amdgcn_mfma_f32_16x16x32_bf16(A4[i], B4[n], acc[i][n], 0, 0, 0);
    __builtin_amdgcn_s_setprio(0);
    __builtin_amdgcn_sched_barrier(0);
    __builtin_amdgcn_s_barrier();

    // ---- sub-phase 1: read A upper half; stage; counted vmcnt; MFMA mh=1 --
#pragma unroll
    for (int i = 0; i < 4; ++i)
      A8[i] = *(const short8_t*)&lds[slot + (wmF + 4 + i) * 512 + l8];
    if (p + 3 < NS) {
      STAGE1(p + 3);
      asm volatile("s_waitcnt vmcnt(8)" ::: "memory");   // slab p+1 landed
    } else if (p + 2 < NS) {
      asm volatile("s_waitcnt vmcnt(4)" ::: "memory");
    } else if (p + 1 < NS) {
      asm volatile("s_waitcnt vmcnt(0)" ::: "memory");
    }
    __builtin_amdgcn_sched_barrier(0);
    __builtin_amdgcn_s_barrier();
    asm volatile("s_waitcnt lgkmcnt(0)" ::: "memory");
    __builtin_amdgcn_sched_barrier(0);
    __builtin_amdgcn_s_setprio(1);
#pragma unroll
    for (int i = 0; i < 4; ++i)
#pragma unroll
      for (int n = 0; n < 4; ++n)
        acc[4 + i][n] = __builtin_amdgcn_mfma_f32_16x16x32_bf16(A8[i], B4[n], acc[4 + i][n], 0, 0, 0);
    __builtin_amdgcn_s_setprio(0);
    __builtin_amdgcn_sched_barrier(0);
    __builtin_amdgcn_s_barrier();   // all reads of slab p done ->
                                    // STAGE(p+4) may overwrite slot p&3
  }

  // ---- epilogue: C/D frag layout col=lane&15, row=(l>>4)*4+r ----
  const int fr = l & 15;
  const int kq = l >> 4;
  const int wm = (tid >> 8) << 7;
  const int wn = ((tid >> 6) & 3) << 6;
#pragma unroll
  for (int m = 0; m < 8; ++m) {
#pragma unroll
    for (int n = 0; n < 4; ++n) {
#pragma unroll
      for (int r = 0; r < 4; ++r) {
        const int gm = m0 + wm + m * 16 + kq * 4 + r;
        const int gn = n0 + wn + n * 16 + fr;
        const float v = acc[m][n][r];
        if constexpr (MODE == 0) {
          short* dst = (short*)Cg;
          const int bh = ((gm >> 11) << 1) + (gn >> 11);
          dst[((size_t)bh << 22) + ((size_t)(gm & 2047) << 11) + (gn & 2047)] = f2bf(v);
        } else if constexpr (MODE == 2) {
          short* dst = (short*)Cg;
          const int bh = ((gm >> 11) << 1) + (gn >> 11);
          dst[((size_t)bh << 22) + ((size_t)(gn & 2047) << 11) + (gm & 2047)] = f2bf(v);
        } else if constexpr (MODE == 3) {
          float* dst = (float*)Cg;
          const float sv = v * 0.022097086912079608f + bias[((z & 1) << 11) + gn];
          dst[((size_t)z << 22) + ((size_t)gm << 11) + gn] = sv;
        } else if constexpr (MODE == 4) {
          short* dst = (short*)Cg;
          const size_t row = ((size_t)(z >> 1) << 11) + gm;
          dst[(row << 12) + ((size_t)(z & 1) << 11) + gn] = f2bf(v);
        } else {
          float* dst = (float*)Cg;
          dst[(size_t)gm * 4096 + gn] = v;
        }
      }
    }
  }
}

// row softmax in place (fp32, 2048 wide) + bf16 copy for the PV GEMM
__global__ __launch_bounds__(256)
void softmax_rows(float* __restrict__ attn, short* __restrict__ outb) {
  float* row  = attn + ((size_t)blockIdx.x << 11);
  short* rowb = outb + ((size_t)blockIdx.x << 11);
  const int tid = threadIdx.x;

  float4 v0 = *(const float4*)(row + tid * 8);
  float4 v1 = *(const float4*)(row + tid * 8 + 4);

  float m = fmaxf(fmaxf(fmaxf(v0.x, v0.y), fmaxf(v0.z, v0.w)),
                  fmaxf(fmaxf(v1.x, v1.y), fmaxf(v1.z, v1.w)));
#pragma unroll
  for (int off = 1; off < 64; off <<= 1) m = fmaxf(m, __shfl_xor(m, off));

  __shared__ float redm[4];
  __shared__ float reds[4];
  if ((tid & 63) == 0) redm[tid >> 6] = m;
  __syncthreads();
  m = fmaxf(fmaxf(redm[0], redm[1]), fmaxf(redm[2], redm[3]));

  float e[8];
  e[0] = expf(v0.x - m); e[1] = expf(v0.y - m); e[2] = expf(v0.z - m); e[3] = expf(v0.w - m);
  e[4] = expf(v1.x - m); e[5] = expf(v1.y - m); e[6] = expf(v1.z - m); e[7] = expf(v1.w - m);
  float s = 0.f;
#pragma unroll
  for (int i = 0; i < 8; ++i) s += e[i];
#pragma unroll
  for (int off = 1; off < 64; off <<= 1) s += __shfl_xor(s, off);
  if ((tid & 63) == 0) reds[tid >> 6] = s;
  __syncthreads();
  s = reds[0] + reds[1] + reds[2] + reds[3];

  const float inv = 1.0f / s;
  float4 o0, o1;
  o0.x = e[0] * inv; o0.y = e[1] * inv; o0.z = e[2] * inv; o0.w = e[3] * inv;
  o1.x = e[4] * inv; o1.y = e[5] * inv; o1.z = e[6] * inv; o1.w = e[7] * inv;
  *(float4*)(row + tid * 8)     = o0;
  *(float4*)(row + tid * 8 + 4) = o1;
  *(short8_t*)(rowb + tid * 8)  = cvt8(o0, o1);
}

extern "C" void kernel_launch(void* const* d_in, const int* in_sizes, int n_in,
                              void* d_out, int out_size, void* d_ws, size_t ws_size,
                              hipStream_t stream) {
  const float* x  = (const float*)d_in[0];
  const float* Wq = (const float*)d_in[1];
  const float* Wk = (const float*)d_in[2];
  const float* Wv = (const float*)d_in[3];
  const float* Wo = (const float*)d_in[4];
  const float* pb = (const float*)d_in[5];

  float* y_out = (float*)d_out;                       // 8*2048*4096 f32
  float* attn  = y_out + (size_t)8 * 2048 * 4096;     // 16*2048*2048 f32

  const size_t NEED = 4ull * 67108864ull * 2ull;      // 512 MB
  if (ws_size < NEED) return;
  short* buf0 = (short*)d_ws;
  short* buf1 = buf0 + 67108864;
  short* buf2 = buf1 + 67108864;
  short* buf3 = buf2 + 67108864;

  short* xb      = buf0;             // x bf16 (16384 x 4096)
  short* qb      = buf1;             // (b,h,t,d)
  short* kb      = buf2;             // (b,h,t,d)
  short* vtb     = buf3;             // (b,h,d,s)
  short* wob     = buf0;             // Wo bf16 (reuses xb after projections)
  short* attn_bf = buf1;             // bf16 probs (reuses qb after scores)
  short* yb      = buf2;             // attn@v bf16 (reuses kb after scores)
  short* wb      = (short*)attn;     // W staging in d_out attn region
                                     // (dead until scores GEMM writes it)

  const dim3 blk512(512);
  const dim3 blk(256);
  const dim3 gcv(2048);
  const dim3 g1k(1024);

  cvt_f32_bf16<<<gcv, blk, 0, stream>>>(x, xb, 67108864 / 8);

  cvt_f32_bf16<<<gcv, blk, 0, stream>>>(Wq, wb, 16777216 / 8);
  gemm256<0><<<g1k, blk512, 0, stream>>>(xb, wb, qb, nullptr);
  cvt_f32_bf16<<<gcv, blk, 0, stream>>>(Wk, wb, 16777216 / 8);
  gemm256<0><<<g1k, blk512, 0, stream>>>(xb, wb, kb, nullptr);
  cvt_f32_bf16<<<gcv, blk, 0, stream>>>(Wv, wb, 16777216 / 8);
  gemm256<2><<<g1k, blk512, 0, stream>>>(xb, wb, vtb, nullptr);

  cvt_f32_bf16<<<gcv, blk, 0, stream>>>(Wo, wob, 16777216 / 8);  // x dead now

  gemm256<3><<<g1k, blk512, 0, stream>>>(qb, kb, attn, pb);
  softmax_rows<<<dim3(32768), blk, 0, stream>>>(attn, attn_bf);
  gemm256<4><<<g1k, blk512, 0, stream>>>(attn_bf, vtb, yb, nullptr);
  gemm256<5><<<g1k, blk512, 0, stream>>>(yb, wob, y_out, nullptr);
}

// Round 6
// 3213.836 us; speedup vs baseline: 1.0017x; 1.0017x over previous
//
#include <hip/hip_runtime.h>
#include <hip/hip_bf16.h>
#include <cstdint>
#include <cstddef>

// ---------------------------------------------------------------------------
// DisentangledMultiHeadAttention: B=8, H=2, T=2048, D=2048, C=4096
// 256x256-tile bf16 MFMA GEMM, 8 waves (2M x 4N), K-slab ring (4 x K=32,
// 128KB LDS), m201-style schedule, NO sched_barrier pinning (m141 lesson):
//   slab p, phase A: {8x ds_read (B all + A lower) ; STAGE0(p+3) ; s_barrier ;
//                     lgkmcnt(0) ; setprio1 ; 16 MFMA ; setprio0 ; s_barrier}
//   slab p, phase B: {4x ds_read (A upper) ; STAGE1(p+3) ; vmcnt(8) counted ;
//                     s_barrier ; lgkmcnt(0) ; setprio1 ; 16 MFMA ; setprio0 ;
//                     s_barrier}
// Reads issued BEFORE the barrier drain during barrier-wait slack (m201
// mechanism). vmcnt never 0 in main loop. WAR on ring slot (p-1)&3 closed by
// lgkmcnt(0)-before-closing-barrier of slab p-1.
// LDS is FRAGMENT-MAJOR: each 1KB MFMA fragment contiguous; lane l reads
// base + l*16B (conflict-free, measured 0); gld_lds writes the identical
// pattern (wave-uniform base + lane*16).
// v stored TRANSPOSED so PV is NT; softmax emits bf16 probs for PV.
// ---------------------------------------------------------------------------

typedef short short8_t __attribute__((ext_vector_type(8)));
typedef float f32x4   __attribute__((ext_vector_type(4)));

__device__ __forceinline__ short f2bf(float f) {
  unsigned u = __builtin_bit_cast(unsigned, f);
  u = (u + 0x7FFFu + ((u >> 16) & 1u)) >> 16;   // round-to-nearest-even
  return (short)u;
}

__device__ __forceinline__ short8_t cvt8(float4 a, float4 b) {
  short8_t r;
  r[0] = f2bf(a.x); r[1] = f2bf(a.y); r[2] = f2bf(a.z); r[3] = f2bf(a.w);
  r[4] = f2bf(b.x); r[5] = f2bf(b.y); r[6] = f2bf(b.z); r[7] = f2bf(b.w);
  return r;
}

__device__ __forceinline__ void gld_lds16(const void* g, void* l) {
  __builtin_amdgcn_global_load_lds(
      (const __attribute__((address_space(1))) void*)g,
      (__attribute__((address_space(3))) void*)l, 16, 0, 0);
}

// fp32 -> bf16 bulk convert, 8 elem/thread, grid-stride
__global__ __launch_bounds__(256)
void cvt_f32_bf16(const float* __restrict__ src, short* __restrict__ dst, int n8) {
  for (int i = blockIdx.x * blockDim.x + threadIdx.x; i < n8;
       i += gridDim.x * blockDim.x) {
    const float4* p = (const float4*)(src + (size_t)i * 8);
    float4 a = p[0], b = p[1];
    *(short8_t*)(dst + (size_t)i * 8) = cvt8(a, b);
  }
}

// MODE 0: q/k proj  C=bf16 (b,h,t,d)                 K=4096
// MODE 2: v proj    C=bf16 (b,h,d,s) [transposed]    K=4096
// MODE 3: scores    C=f32 scale+bias -> attn (d_out) K=2048, batched z
// MODE 4: PV        C=bf16 (b*T+t, h*D+d)            K=2048, batched z
// MODE 5: out proj  C=f32 y (d_out)                  K=4096
template<int MODE>
__global__ __launch_bounds__(512, 2)
void gemm256(const short* __restrict__ Ag, const short* __restrict__ Bg,
             void* __restrict__ Cg, const float* __restrict__ bias) {
  constexpr int K  = (MODE == 3 || MODE == 4) ? 2048 : 4096;
  constexpr int NS = K / 32;   // K-slabs

  // ring: 4 slots x 32KB; per slot: A frags [16 x 512 shorts], then B frags.
  __shared__ short lds[65536];

  const int tid = threadIdx.x;

  // T1: bijective XCD swizzle (gridDim.x = 1024, divisible by 8)
  const int bid = blockIdx.x;
  const int id  = (bid & 7) * (gridDim.x >> 3) + (bid >> 3);

  int m0, n0, z = 0;
  size_t aoff = 0, boff = 0;
  if constexpr (MODE == 3 || MODE == 4) {
    z  = id >> 6;                       // 16 batches
    m0 = ((id >> 3) & 7) << 8;          // 8 m-tiles
    n0 = (id & 7) << 8;                 // 8 n-tiles
    aoff = boff = (size_t)z << 22;
  } else {
    m0 = (id >> 4) << 8;                // 64 m-tiles
    n0 = (id & 15) << 8;                // 16 n-tiles (n fastest: A-panel reuse)
  }

  const int l = tid & 63;
  const int w = tid >> 6;               // wave id 0..7

  // ---- staging (frag-major): frag f of a slab = rows [f*16, f*16+16) x k32,
  //      lane-ordered: lane l holds (row f*16+(l&15), k (l>>4)*8 .. +7).
  //      Wave w stages A frags {2w, 2w+1} and B frags {2w, 2w+1} per slab.
  const int srow = l & 15;
  const int skol = (l >> 4) * 8;
  const short* ApS  = Ag + aoff + (size_t)(m0 + 2 * w * 16 + srow) * K + skol;
  const short* ApS2 = ApS + (size_t)16 * K;
  const short* BpS  = Bg + boff + (size_t)(n0 + 2 * w * 16 + srow) * K + skol;
  const short* BpS2 = BpS + (size_t)16 * K;

  auto STAGE0 = [&](int t) {           // first halves (A frag 2w, B frag 2w)
    const int s = (t & 3) << 14;
    const int k = t * 32;
    gld_lds16(ApS + k, &lds[s + 2 * w * 512]);
    gld_lds16(BpS + k, &lds[s + 8192 + 2 * w * 512]);
  };
  auto STAGE1 = [&](int t) {           // second halves (frags 2w+1)
    const int s = (t & 3) << 14;
    const int k = t * 32;
    gld_lds16(ApS2 + k, &lds[s + (2 * w + 1) * 512]);
    gld_lds16(BpS2 + k, &lds[s + 8192 + (2 * w + 1) * 512]);
  };

  // ---- fragment read bases (conflict-free: base + l*16B) ----
  const int wmF = (tid >> 8) * 8;         // wave m frag base (0 / 8)
  const int wnF = ((tid >> 6) & 3) * 4;   // wave n frag base (0/4/8/12)
  const int l8  = l * 8;

  f32x4 acc[8][4] = {};

  STAGE0(0); STAGE1(0); STAGE0(1); STAGE1(1); STAGE0(2); STAGE1(2);
  asm volatile("s_waitcnt vmcnt(8)" ::: "memory");   // slab 0 landed
  __builtin_amdgcn_s_barrier();

  for (int p = 0; p < NS; ++p) {
    const int slot = (p & 3) << 14;
    short8_t A4[4], B4[4], A8[4];

    // ---- phase A: read B (all n) + A lower half; stage; MFMA lower ----
#pragma unroll
    for (int n = 0; n < 4; ++n)
      B4[n] = *(const short8_t*)&lds[slot + 8192 + (wnF + n) * 512 + l8];
#pragma unroll
    for (int i = 0; i < 4; ++i)
      A4[i] = *(const short8_t*)&lds[slot + (wmF + i) * 512 + l8];
    if (p + 3 < NS) STAGE0(p + 3);
    __builtin_amdgcn_s_barrier();
    asm volatile("s_waitcnt lgkmcnt(0)" ::: "memory");
    __builtin_amdgcn_s_setprio(1);
#pragma unroll
    for (int i = 0; i < 4; ++i)
#pragma unroll
      for (int n = 0; n < 4; ++n)
        acc[i][n] = __builtin_amdgcn_mfma_f32_16x16x32_bf16(A4[i], B4[n], acc[i][n], 0, 0, 0);
    __builtin_amdgcn_s_setprio(0);
    __builtin_amdgcn_s_barrier();

    // ---- phase B: read A upper half; stage; counted vmcnt; MFMA upper ----
#pragma unroll
    for (int i = 0; i < 4; ++i)
      A8[i] = *(const short8_t*)&lds[slot + (wmF + 4 + i) * 512 + l8];
    if (p + 3 < NS) {
      STAGE1(p + 3);
      asm volatile("s_waitcnt vmcnt(8)" ::: "memory");   // slab p+1 landed
    } else if (p + 2 < NS) {
      asm volatile("s_waitcnt vmcnt(4)" ::: "memory");
    } else if (p + 1 < NS) {
      asm volatile("s_waitcnt vmcnt(0)" ::: "memory");
    }
    __builtin_amdgcn_s_barrier();
    asm volatile("s_waitcnt lgkmcnt(0)" ::: "memory");
    __builtin_amdgcn_s_setprio(1);
#pragma unroll
    for (int i = 0; i < 4; ++i)
#pragma unroll
      for (int n = 0; n < 4; ++n)
        acc[4 + i][n] = __builtin_amdgcn_mfma_f32_16x16x32_bf16(A8[i], B4[n], acc[4 + i][n], 0, 0, 0);
    __builtin_amdgcn_s_setprio(0);
    __builtin_amdgcn_s_barrier();   // all reads of slab p drained above ->
                                    // STAGE(p+4) may overwrite slot p&3
  }

  // ---- epilogue: C/D frag layout col=lane&15, row=(l>>4)*4+r ----
  const int fr = l & 15;
  const int kq = l >> 4;
  const int wm = (tid >> 8) << 7;
  const int wn = ((tid >> 6) & 3) << 6;
#pragma unroll
  for (int m = 0; m < 8; ++m) {
#pragma unroll
    for (int n = 0; n < 4; ++n) {
#pragma unroll
      for (int r = 0; r < 4; ++r) {
        const int gm = m0 + wm + m * 16 + kq * 4 + r;
        const int gn = n0 + wn + n * 16 + fr;
        const float v = acc[m][n][r];
        if constexpr (MODE == 0) {
          short* dst = (short*)Cg;
          const int bh = ((gm >> 11) << 1) + (gn >> 11);
          dst[((size_t)bh << 22) + ((size_t)(gm & 2047) << 11) + (gn & 2047)] = f2bf(v);
        } else if constexpr (MODE == 2) {
          short* dst = (short*)Cg;
          const int bh = ((gm >> 11) << 1) + (gn >> 11);
          dst[((size_t)bh << 22) + ((size_t)(gn & 2047) << 11) + (gm & 2047)] = f2bf(v);
        } else if constexpr (MODE == 3) {
          float* dst = (float*)Cg;
          const float sv = v * 0.022097086912079608f + bias[((z & 1) << 11) + gn];
          dst[((size_t)z << 22) + ((size_t)gm << 11) + gn] = sv;
        } else if constexpr (MODE == 4) {
          short* dst = (short*)Cg;
          const size_t row = ((size_t)(z >> 1) << 11) + gm;
          dst[(row << 12) + ((size_t)(z & 1) << 11) + gn] = f2bf(v);
        } else {
          float* dst = (float*)Cg;
          dst[(size_t)gm * 4096 + gn] = v;
        }
      }
    }
  }
}

// row softmax in place (fp32, 2048 wide) + bf16 copy for the PV GEMM
__global__ __launch_bounds__(256)
void softmax_rows(float* __restrict__ attn, short* __restrict__ outb) {
  float* row  = attn + ((size_t)blockIdx.x << 11);
  short* rowb = outb + ((size_t)blockIdx.x << 11);
  const int tid = threadIdx.x;

  float4 v0 = *(const float4*)(row + tid * 8);
  float4 v1 = *(const float4*)(row + tid * 8 + 4);

  float m = fmaxf(fmaxf(fmaxf(v0.x, v0.y), fmaxf(v0.z, v0.w)),
                  fmaxf(fmaxf(v1.x, v1.y), fmaxf(v1.z, v1.w)));
#pragma unroll
  for (int off = 1; off < 64; off <<= 1) m = fmaxf(m, __shfl_xor(m, off));

  __shared__ float redm[4];
  __shared__ float reds[4];
  if ((tid & 63) == 0) redm[tid >> 6] = m;
  __syncthreads();
  m = fmaxf(fmaxf(redm[0], redm[1]), fmaxf(redm[2], redm[3]));

  float e[8];
  e[0] = expf(v0.x - m); e[1] = expf(v0.y - m); e[2] = expf(v0.z - m); e[3] = expf(v0.w - m);
  e[4] = expf(v1.x - m); e[5] = expf(v1.y - m); e[6] = expf(v1.z - m); e[7] = expf(v1.w - m);
  float s = 0.f;
#pragma unroll
  for (int i = 0; i < 8; ++i) s += e[i];
#pragma unroll
  for (int off = 1; off < 64; off <<= 1) s += __shfl_xor(s, off);
  if ((tid & 63) == 0) reds[tid >> 6] = s;
  __syncthreads();
  s = reds[0] + reds[1] + reds[2] + reds[3];

  const float inv = 1.0f / s;
  float4 o0, o1;
  o0.x = e[0] * inv; o0.y = e[1] * inv; o0.z = e[2] * inv; o0.w = e[3] * inv;
  o1.x = e[4] * inv; o1.y = e[5] * inv; o1.z = e[6] * inv; o1.w = e[7] * inv;
  *(float4*)(row + tid * 8)     = o0;
  *(float4*)(row + tid * 8 + 4) = o1;
  *(short8_t*)(rowb + tid * 8)  = cvt8(o0, o1);
}

extern "C" void kernel_launch(void* const* d_in, const int* in_sizes, int n_in,
                              void* d_out, int out_size, void* d_ws, size_t ws_size,
                              hipStream_t stream) {
  const float* x  = (const float*)d_in[0];
  const float* Wq = (const float*)d_in[1];
  const float* Wk = (const float*)d_in[2];
  const float* Wv = (const float*)d_in[3];
  const float* Wo = (const float*)d_in[4];
  const float* pb = (const float*)d_in[5];

  float* y_out = (float*)d_out;                       // 8*2048*4096 f32
  float* attn  = y_out + (size_t)8 * 2048 * 4096;     // 16*2048*2048 f32

  const size_t NEED = 4ull * 67108864ull * 2ull;      // 512 MB
  if (ws_size < NEED) return;
  short* buf0 = (short*)d_ws;
  short* buf1 = buf0 + 67108864;
  short* buf2 = buf1 + 67108864;
  short* buf3 = buf2 + 67108864;

  short* xb      = buf0;             // x bf16 (16384 x 4096)
  short* qb      = buf1;             // (b,h,t,d)
  short* kb      = buf2;             // (b,h,t,d)
  short* vtb     = buf3;             // (b,h,d,s)
  short* wob     = buf0;             // Wo bf16 (reuses xb after projections)
  short* attn_bf = buf1;             // bf16 probs (reuses qb after scores)
  short* yb      = buf2;             // attn@v bf16 (reuses kb after scores)
  short* wb      = (short*)attn;     // W staging in d_out attn region
                                     // (dead until scores GEMM writes it)

  const dim3 blk512(512);
  const dim3 blk(256);
  const dim3 gcv(2048);
  const dim3 g1k(1024);

  cvt_f32_bf16<<<gcv, blk, 0, stream>>>(x, xb, 67108864 / 8);

  cvt_f32_bf16<<<gcv, blk, 0, stream>>>(Wq, wb, 16777216 / 8);
  gemm256<0><<<g1k, blk512, 0, stream>>>(xb, wb, qb, nullptr);
  cvt_f32_bf16<<<gcv, blk, 0, stream>>>(Wk, wb, 16777216 / 8);
  gemm256<0><<<g1k, blk512, 0, stream>>>(xb, wb, kb, nullptr);
  cvt_f32_bf16<<<gcv, blk, 0, stream>>>(Wv, wb, 16777216 / 8);
  gemm256<2><<<g1k, blk512, 0, stream>>>(xb, wb, vtb, nullptr);

  cvt_f32_bf16<<<gcv, blk, 0, stream>>>(Wo, wob, 16777216 / 8);  // x dead now

  gemm256<3><<<g1k, blk512, 0, stream>>>(qb, kb, attn, pb);
  softmax_rows<<<dim3(32768), blk, 0, stream>>>(attn, attn_bf);
  gemm256<4><<<g1k, blk512, 0, stream>>>(attn_bf, vtb, yb, nullptr);
  gemm256<5><<<g1k, blk512, 0, stream>>>(yb, wob, y_out, nullptr);
}